// Round 1
// baseline (456.442 us; speedup 1.0000x reference)
//
#include <hip/hip_runtime.h>
#include <hip/hip_bf16.h>

typedef __bf16 bf16x8 __attribute__((ext_vector_type(8)));
typedef __bf16 bf16x4 __attribute__((ext_vector_type(4)));
typedef __bf16 bf16x2 __attribute__((ext_vector_type(2)));
typedef float f32x4 __attribute__((ext_vector_type(4)));

#define NROWS 100000
#define NSTRIPS 6250   // 100000 / 16, exact
#define EPS 1e-5f
#define SLOPE 0.2f
#define INVN 1e-5f     // 1.0f / 100000

__device__ __forceinline__ bf16x8 cvt8(float4 x0, float4 x1) {
    bf16x8 o;
    o[0] = (__bf16)x0.x; o[1] = (__bf16)x0.y; o[2] = (__bf16)x0.z; o[3] = (__bf16)x0.w;
    o[4] = (__bf16)x1.x; o[5] = (__bf16)x1.y; o[6] = (__bf16)x1.z; o[7] = (__bf16)x1.w;
    return o;
}

// ---- streaming GEMM: Y = LeakyReLU(A @ W^T + bias), + column sum/sumsq --------
// Tall-skinny (M=100000, K<=256, N<=256): W-fragments live entirely in registers.
// v2 changes vs previous session:
//  * 1-deep software prefetch: strip s+1's global loads issue before strip s's
//    MFMAs (ping-pong raw buffers, compile-time indices -> no scratch).
//  * swapped MFMA operands: mfma(W_frag, A_frag) puts 4 CONSECUTIVE output
//    columns of one row in each lane -> one 8B bf16x4 store per acc (was 4x
//    scalar 2B stores). Store instr count /4, 16x32B segments per instr.
// C/D layout (verified mapping): col=l16 -> X row, row=quad*4+r -> W col.
template <int KT, int NI, int WAVES, bool F32IN>
__global__ __launch_bounds__(WAVES * 64, 2)
void gemm_stream(const __bf16* __restrict__ A, const float* __restrict__ A32,
                 const __bf16* __restrict__ W, const float* __restrict__ W32,
                 const float* __restrict__ bias, __bf16* __restrict__ Y,
                 float* __restrict__ sum, float* __restrict__ sumsq)
{
    constexpr int KS = KT / 32;
    constexpr int NCOLS = NI * 16 * WAVES;
    const int wave = threadIdx.x >> 6, lane = threadIdx.x & 63;
    const int quad = lane >> 4, l16 = lane & 15;
    const int c0 = wave * (NI * 16);

    // W fragments (MFMA A-operand): lane holds W[c0+ni*16+l16][ks*32+quad*8 ..+8]
    bf16x8 bfrag[NI][KS];
    f32x4 bias4[NI];  // bias for this lane's 4 output columns: c0+ni*16+quad*4+r
    #pragma unroll
    for (int ni = 0; ni < NI; ++ni) {
        const int colb = c0 + ni * 16;
        const float4 b4 = *(const float4*)(bias + colb + quad * 4);
        bias4[ni][0] = b4.x; bias4[ni][1] = b4.y; bias4[ni][2] = b4.z; bias4[ni][3] = b4.w;
        const int col = colb + l16;
        #pragma unroll
        for (int ks = 0; ks < KS; ++ks) {
            const int k = ks * 32 + quad * 8;
            if constexpr (F32IN) {
                const float* p = W32 + (size_t)col * KT + k;
                bfrag[ni][ks] = cvt8(*(const float4*)p, *(const float4*)(p + 4));
            } else {
                bfrag[ni][ks] = *(const bf16x8*)(W + (size_t)col * KT + k);
            }
        }
    }

    f32x4 csum[NI] = {}, csq[NI] = {};
    float4 rawf[2][KS][2];   // F32IN raw prefetch buffers (dead-code-eliminated otherwise)
    bf16x8 rawb[2][KS];      // bf16 raw prefetch buffers

#define LOAD_STRIP(BUF, S) do {                                                   \
        const int row_ = (S) * 16 + l16;                                          \
        _Pragma("unroll")                                                         \
        for (int ks = 0; ks < KS; ++ks) {                                         \
            const int k_ = ks * 32 + quad * 8;                                    \
            if constexpr (F32IN) {                                                \
                const float* p_ = A32 + (size_t)row_ * KT + k_;                   \
                rawf[BUF][ks][0] = *(const float4*)p_;                            \
                rawf[BUF][ks][1] = *(const float4*)(p_ + 4);                      \
            } else {                                                              \
                rawb[BUF][ks] = *(const bf16x8*)(A + (size_t)row_ * KT + k_);     \
            }                                                                     \
        }                                                                         \
    } while (0)

#define COMPUTE_STORE(BUF, S) do {                                                \
        bf16x8 af_[KS];                                                           \
        _Pragma("unroll")                                                         \
        for (int ks = 0; ks < KS; ++ks) {                                         \
            if constexpr (F32IN) af_[ks] = cvt8(rawf[BUF][ks][0], rawf[BUF][ks][1]); \
            else                 af_[ks] = rawb[BUF][ks];                         \
        }                                                                         \
        f32x4 acc_[NI] = {};                                                      \
        _Pragma("unroll")                                                         \
        for (int ks = 0; ks < KS; ++ks)                                           \
            _Pragma("unroll")                                                     \
            for (int ni = 0; ni < NI; ++ni)                                       \
                acc_[ni] = __builtin_amdgcn_mfma_f32_16x16x32_bf16(               \
                    bfrag[ni][ks], af_[ks], acc_[ni], 0, 0, 0);                   \
        const int row_ = (S) * 16 + l16;                                          \
        __bf16* yp_ = Y + (size_t)row_ * NCOLS + c0 + quad * 4;                   \
        _Pragma("unroll")                                                         \
        for (int ni = 0; ni < NI; ++ni) {                                         \
            f32x4 y_;                                                             \
            _Pragma("unroll")                                                     \
            for (int r = 0; r < 4; ++r) {                                         \
                float v_ = acc_[ni][r] + bias4[ni][r];                            \
                v_ = (v_ > 0.f) ? v_ : SLOPE * v_;                                \
                y_[r] = v_;                                                       \
            }                                                                     \
            csum[ni] += y_;                                                       \
            csq[ni]  += y_ * y_;                                                  \
            bf16x4 o_;                                                            \
            o_[0] = (__bf16)y_[0]; o_[1] = (__bf16)y_[1];                         \
            o_[2] = (__bf16)y_[2]; o_[3] = (__bf16)y_[3];                         \
            *(bf16x4*)(yp_ + ni * 16) = o_;                                       \
        }                                                                         \
    } while (0)

    int s = blockIdx.x;
    const int stride = gridDim.x;
    if (s < NSTRIPS) {
        LOAD_STRIP(0, s);
        while (true) {
            int sn = s + stride;
            if (sn < NSTRIPS) LOAD_STRIP(1, sn);   // prefetch next strip
            COMPUTE_STORE(0, s);
            s = sn;
            if (s >= NSTRIPS) break;
            sn = s + stride;
            if (sn < NSTRIPS) LOAD_STRIP(0, sn);
            COMPUTE_STORE(1, s);
            s = sn;
            if (s >= NSTRIPS) break;
        }
    }
#undef LOAD_STRIP
#undef COMPUTE_STORE

    // column sums: lane holds cols c0+ni*16+quad*4+r, rows = l16 (over strips).
    // Reduce across the 16 l16-lanes of each quad, then one atomic per column.
    #pragma unroll
    for (int ni = 0; ni < NI; ++ni) {
        #pragma unroll
        for (int r = 0; r < 4; ++r) {
            float sv = csum[ni][r], qv = csq[ni][r];
            sv += __shfl_xor(sv, 1);  qv += __shfl_xor(qv, 1);
            sv += __shfl_xor(sv, 2);  qv += __shfl_xor(qv, 2);
            sv += __shfl_xor(sv, 4);  qv += __shfl_xor(qv, 4);
            sv += __shfl_xor(sv, 8);  qv += __shfl_xor(qv, 8);
            if (l16 == 0) {
                const int col = c0 + ni * 16 + quad * 4 + r;
                atomicAdd(&sum[col], sv);
                atomicAdd(&sumsq[col], qv);
            }
        }
    }
}

// ---- fused stats + fold: every block recomputes s,t from column sums (cheap),
// then folds BN into the next layer: W' = W*diag(s) (bf16), b' = b + W@t.
// Removes the 1-block stats_k launches (stream bubbles) for layers 1,2.
__global__ void fold_stats_k(const float* __restrict__ sum, const float* __restrict__ sumsq,
                             const float* __restrict__ g, const float* __restrict__ beta,
                             const float* __restrict__ W, const float* __restrict__ b,
                             __bf16* __restrict__ Wf, float* __restrict__ bf_, int K)
{
    __shared__ float s_sh[256], t_sh[256];
    const int n = blockIdx.x, lane = threadIdx.x;  // 64 threads = 1 wave
    for (int k = lane; k < K; k += 64) {
        float m = sum[k] * INVN;
        float v = sumsq[k] * INVN - m * m;
        float sc = g[k] * rsqrtf(v + EPS);
        s_sh[k] = sc;
        t_sh[k] = beta[k] - m * sc;
    }
    __syncthreads();
    float dot = 0.f;
    for (int k = lane; k < K; k += 64) {
        float w = W[(size_t)n * K + k];
        Wf[(size_t)n * K + k] = (__bf16)(w * s_sh[k]);
        dot += w * t_sh[k];
    }
    #pragma unroll
    for (int off = 32; off; off >>= 1) dot += __shfl_down(dot, off);
    if (lane == 0) bf_[n] = b[n] + dot;
}

// ---- fused finalize: one wave per node row.
//  * computes s3,t3 inline per lane from sum3/sq3 (drops stats_k + its bubble)
//  * F = Y3*s3 + t3  (the 'f' output, fp32)
//  * node_update = s3 * mean_k(Y3[neigh]) + t3  (BN after mean; linear)
// Fusing drops one full sequential 25.6 MB re-read of Y3 + one launch.
__global__ __launch_bounds__(256)
void finalize_k(const __bf16* __restrict__ Y3, const int* __restrict__ idx,
                const float* __restrict__ sum3, const float* __restrict__ sq3,
                const float* __restrict__ g3, const float* __restrict__ be3,
                float* __restrict__ F, float* __restrict__ out, int N)
{
    const int row = blockIdx.x * 4 + (threadIdx.x >> 6);  // one row per wave
    if (row >= N) return;
    const int lane = threadIdx.x & 63;
    const int c = lane * 2;

    const float2 sm = *(const float2*)(sum3 + c);
    const float2 sq = *(const float2*)(sq3 + c);
    const float2 gg = *(const float2*)(g3 + c);
    const float2 bb = *(const float2*)(be3 + c);
    const float m0 = sm.x * INVN, m1 = sm.y * INVN;
    const float v0 = sq.x * INVN - m0 * m0, v1 = sq.y * INVN - m1 * m1;
    const float s0 = gg.x * rsqrtf(v0 + EPS), s1 = gg.y * rsqrtf(v1 + EPS);
    const float t0 = bb.x - m0 * s0, t1 = bb.y - m1 * s1;

    bf16x2 own = *(const bf16x2*)(Y3 + (size_t)row * 128 + c);
    float2 f;
    f.x = (float)own[0] * s0 + t0;
    f.y = (float)own[1] * s1 + t1;
    *(float2*)(F + (size_t)row * 128 + c) = f;

    const int* ib = idx + (size_t)row * 16;
    float a0 = 0.f, a1 = 0.f;
    #pragma unroll
    for (int k = 0; k < 16; ++k) {
        const int j = ib[k];  // wave-uniform -> scalar load
        bf16x2 v = *(const bf16x2*)(Y3 + (size_t)j * 128 + c);
        a0 += (float)v[0];
        a1 += (float)v[1];
    }
    float2 o;
    o.x = a0 * 0.0625f * s0 + t0;
    o.y = a1 * 0.0625f * s1 + t1;
    *(float2*)(out + (size_t)row * 128 + c) = o;
}

extern "C" void kernel_launch(void* const* d_in, const int* in_sizes, int n_in,
                              void* d_out, int out_size, void* d_ws, size_t ws_size,
                              hipStream_t stream)
{
    const float* X   = (const float*)d_in[0];
    const int*   idx = (const int*)d_in[1];
    // d_in[2] = prob_retained (unused, ==1)
    const float* W1  = (const float*)d_in[3];
    const float* b1  = (const float*)d_in[4];
    const float* g1  = (const float*)d_in[5];
    const float* be1 = (const float*)d_in[6];
    const float* W2  = (const float*)d_in[7];
    const float* b2  = (const float*)d_in[8];
    const float* g2  = (const float*)d_in[9];
    const float* be2 = (const float*)d_in[10];
    const float* W3  = (const float*)d_in[11];
    const float* b3  = (const float*)d_in[12];
    const float* g3  = (const float*)d_in[13];
    const float* be3 = (const float*)d_in[14];

    char* ws = (char*)d_ws;
    float* sum1 = (float*)(ws + 0);
    float* sq1  = (float*)(ws + 1024);
    float* sum2 = (float*)(ws + 2048);
    float* sq2  = (float*)(ws + 3072);
    float* sum3 = (float*)(ws + 4096);
    float* sq3  = (float*)(ws + 4608);
    float* b2f  = (float*)(ws + 10240);
    float* b3f  = (float*)(ws + 11264);
    __bf16* W2f = (__bf16*)(ws + 13312);            // 256*256*2 = 131072 B
    __bf16* W3f = (__bf16*)(ws + 144384);           // 128*256*2 = 65536 B
    __bf16* Y1  = (__bf16*)(ws + (1 << 20));                   // [N,256] bf16 51.2 MB
    __bf16* Y2  = (__bf16*)(ws + (1 << 20) + 51200000);        // [N,256] bf16 51.2 MB
    __bf16* Y3  = Y1;  // [N,128]; Y1 dead after gemm2 (gemm3 reads only Y2)

    float* out_nu = (float*)d_out;                  // node_update [N,128] fp32
    float* F      = out_nu + (size_t)NROWS * 128;   // f [N,128] fp32

    hipMemsetAsync(d_ws, 0, 5120, stream);  // zero sum/sumsq accumulators

    // layer 1: X[100000,128] @ W1[256,128]^T (fp32 converted inline)
    // 256 thr (4 waves), 2 blocks/CU
    gemm_stream<128, 4, 4, true><<<512, 256, 0, stream>>>(
        nullptr, X, nullptr, W1, b1, Y1, sum1, sq1);
    fold_stats_k<<<256, 64, 0, stream>>>(sum1, sq1, g1, be1, W2, b2, W2f, b2f, 256);

    // layer 2: Y1[100000,256] @ W2'[256,256]^T -> Y2
    // 512 thr (8 waves, NI=2 keeps W-frag at 64 VGPR), 1 block/CU
    gemm_stream<256, 2, 8, false><<<256, 512, 0, stream>>>(
        Y1, nullptr, W2f, nullptr, b2f, Y2, sum2, sq2);
    fold_stats_k<<<128, 64, 0, stream>>>(sum2, sq2, g2, be2, W3, b3, W3f, b3f, 256);

    // layer 3: Y2[100000,256] @ W3'[128,256]^T -> raw Y3 (pre-BN) into Y1 region
    gemm_stream<256, 1, 8, false><<<256, 512, 0, stream>>>(
        Y2, nullptr, W3f, nullptr, b3f, Y3, sum3, sq3);

    // fused: stats3 + f-output + neighbor-mean
    finalize_k<<<25000, 256, 0, stream>>>(Y3, idx, sum3, sq3, g3, be3, F, out_nu, NROWS);
}